// Round 16
// baseline (436.302 us; speedup 1.0000x reference)
//
#include <hip/hip_runtime.h>

typedef float f32x4 __attribute__((ext_vector_type(4)));
typedef short bf16x8v __attribute__((ext_vector_type(8)));
typedef unsigned short u16;
typedef unsigned int u32;

#define DEVI static __device__ __forceinline__

constexpr int R_ = 128, L_ = 384, D_ = 256, H_ = 8;
constexpr int RL_ = R_ * L_;          // 49152

// ---- ws byte offsets ----
constexpr size_t A_OFF = 0;                    // 25,165,824  xn bf16 / vt / xn2
constexpr size_t B_OFF = 25165824;             // 75,497,472  proj bf16 / height attn out
constexpr size_t C_OFF = 100663296;            // 25,165,824  width attn out bf16 (l-major)
constexpr size_t D_OFF = 125829120;            //  4,718,592  height dots f32
constexpr size_t F_OFF = 130547712;            //  2,359,296  height attn bf16
constexpr size_t EW_W    = 132907008;          // wqkv^T bf16 [768][256]
constexpr size_t EW_H    = 133300224;          // hqkv^T bf16 [768][256]
constexpr size_t EW_OT   = 133693440;          // oT bf16 [256][512]
constexpr size_t EW_FF1  = 133955584;          // ff1^T bf16 [1024][256]
constexpr size_t EW_FF2  = 134479872;          // ff2^T bf16 [256][1024]
constexpr size_t EW_WP   = 135004160;          // w' f32 [128][8]
constexpr size_t EW_WC   = 135008256;          // W[8],C[8] f32
constexpr size_t EW_BS   = 135008320;          // 0.5*(wout_b+hout_b) f32 [256]

DEVI u16 f2bf(float f) {
  unsigned int b = __builtin_bit_cast(unsigned int, f);
  b += 0x7FFFu + ((b >> 16) & 1u);
  return (u16)(b >> 16);
}

#define MFMA16(a, b, c) __builtin_amdgcn_mfma_f32_16x16x32_bf16(a, b, c, 0, 0, 0)

typedef __attribute__((address_space(3))) u32 lds_u32;
typedef const __attribute__((address_space(1))) u32 glb_u32;
DEVI void gld16(const void* g, void* l) {
  __builtin_amdgcn_global_load_lds((glb_u32*)g, (lds_u32*)l, 16, 0, 0);
}

// ---------------- batched prep: all weight transposes + pair-bias prep, ONE launch ----------
__global__ __launch_bounds__(256) void prep_kernel(
    const float* __restrict__ wq, const float* __restrict__ wkv,
    const float* __restrict__ hq, const float* __restrict__ hkv,
    const float* __restrict__ ff1, const float* __restrict__ ff2,
    const float* __restrict__ wout, const float* __restrict__ hout,
    u16* __restrict__ wT_w, u16* __restrict__ wT_h,
    u16* __restrict__ f1T, u16* __restrict__ f2T, u16* __restrict__ oT,
    const float* __restrict__ png, const float* __restrict__ pnb,
    const float* __restrict__ plw,
    const float* __restrict__ woutb, const float* __restrict__ houtb,
    float* __restrict__ wprime, float* __restrict__ wc, float* __restrict__ bsum) {
  int b = blockIdx.x;
  if (b < 4096) {
    const float* src; u16* dst; int N, dstK, koff, base;
    if (b < 256)       { src = wq;   dst = wT_w;          N = 256;  dstK = 256;  koff = 0;   base = 0; }
    else if (b < 768)  { src = wkv;  dst = wT_w + 65536;  N = 512;  dstK = 256;  koff = 0;   base = 256; }
    else if (b < 1024) { src = hq;   dst = wT_h;          N = 256;  dstK = 256;  koff = 0;   base = 768; }
    else if (b < 1536) { src = hkv;  dst = wT_h + 65536;  N = 512;  dstK = 256;  koff = 0;   base = 1024; }
    else if (b < 2560) { src = ff1;  dst = f1T;           N = 1024; dstK = 256;  koff = 0;   base = 1536; }
    else if (b < 3584) { src = ff2;  dst = f2T;           N = 256;  dstK = 1024; koff = 0;   base = 2560; }
    else if (b < 3840) { src = wout; dst = oT;            N = 256;  dstK = 512;  koff = 0;   base = 3584; }
    else               { src = hout; dst = oT;            N = 256;  dstK = 512;  koff = 256; base = 3840; }
    int idx = (b - base) * 256 + threadIdx.x;
    int k = idx / N, n = idx - k * N;
    dst[(size_t)n * dstK + koff + k] = f2bf(src[idx]);
  } else {
    int p = threadIdx.x;
    if (p < 128) {
      float g = png[p];
      #pragma unroll
      for (int h = 0; h < 8; ++h) wprime[p * 8 + h] = g * plw[p * 8 + h];
      bsum[p] = 0.5f * (woutb[p] + houtb[p]);
      bsum[p + 128] = 0.5f * (woutb[p + 128] + houtb[p + 128]);
    }
    if (p == 0) {
      for (int h = 0; h < 8; ++h) {
        float W = 0.f, C = 0.f;
        for (int q = 0; q < 128; ++q) { W += png[q] * plw[q * 8 + h]; C += pnb[q] * plw[q * 8 + h]; }
        wc[h] = W; wc[8 + h] = C;
      }
    }
  }
}

// ---------------- LN over 256 channels, one wave per row ----------------
DEVI void ln_store(float4 v, const float* __restrict__ g, const float* __restrict__ b,
                   u16* __restrict__ dst, int lane) {
  float s1 = v.x + v.y + v.z + v.w;
  float s2 = v.x * v.x + v.y * v.y + v.z * v.z + v.w * v.w;
  #pragma unroll
  for (int off = 1; off < 64; off <<= 1) { s1 += __shfl_xor(s1, off); s2 += __shfl_xor(s2, off); }
  float mu = s1 * (1.f / 256.f);
  float rstd = rsqrtf(s2 * (1.f / 256.f) - mu * mu + 1e-5f);
  float4 gg = *(const float4*)(g + lane * 4);
  float4 bb = *(const float4*)(b + lane * 4);
  ushort4 o = make_ushort4(f2bf((v.x - mu) * rstd * gg.x + bb.x),
                           f2bf((v.y - mu) * rstd * gg.y + bb.y),
                           f2bf((v.z - mu) * rstd * gg.z + bb.z),
                           f2bf((v.w - mu) * rstd * gg.w + bb.w));
  *(ushort4*)dst = o;
}

__global__ __launch_bounds__(256) void ln1_kernel(const float* __restrict__ x,
                                                  const float* __restrict__ g,
                                                  const float* __restrict__ b,
                                                  u16* __restrict__ out) {
  int wid = (blockIdx.x * 256 + threadIdx.x) >> 6;
  if (wid >= RL_) return;
  int lane = threadIdx.x & 63;
  float4 v = *(const float4*)(x + (size_t)wid * 256 + lane * 4);
  ln_store(v, g, b, out + (size_t)wid * 256 + lane * 4, lane);
}

// ---------------- gemm128: BK=32, dbuf LDS (32KB), counted vmcnt, split-A, perm, xadd ---
// GRID MAPPING: blockIdx.y = M-tile, blockIdx.x = N-tile (A-panel reuse is consecutive).
// permA: 0=identity, 1: phys=(row&127)*384+(row>>7), 2: phys=(row%384)*128+row/384
// flags: 1=out bf16 (LDS-staged), 2=beta f32 (scalar path), 4=relu, 8=atomicAdd f32,
//        16=add Xadd[ci] (staged f32 path, coalesced)
__global__ __launch_bounds__(256) void gemm128_kernel(
    const u16* __restrict__ A, const u16* __restrict__ A2, const u16* __restrict__ B,
    void* __restrict__ Cv, const float* __restrict__ bias, const float* __restrict__ Xadd,
    int M, int N, int K,
    int lda, long long kasb, int ldbn, long long kbsb, int ldc, long long cnsb,
    long long abase, long long bbase, long long cbase, int ksplit, int permA,
    int Z2, long long as1, long long as2, long long bs1, long long bs2,
    long long cs1, long long cs2,
    float alpha, int flags) {
  __shared__ __align__(16) u16 SM[16384];
  int z = blockIdx.z, z1 = z / Z2, z2 = z - z1 * Z2;
  long long aoff = abase + z1 * as1 + z2 * as2;
  long long boff = bbase + z1 * bs1 + z2 * bs2;
  long long coff = cbase + z1 * cs1 + z2 * cs2;
  int m0 = blockIdx.y * 128, n0 = blockIdx.x * 128;   // swapped mapping
  int tid = threadIdx.x, lane = tid & 63, w = tid >> 6;
  int wm = w >> 1, wn = w & 1;

  const u16* pA[2]; const u16* pA2[2]; const u16* pB[2];
  #pragma unroll
  for (int q = 0; q < 2; ++q) {
    int row = (w * 2 + q) * 16 + (lane >> 2);
    int g = (lane & 3) ^ ((row >> 1) & 3);
    int ar = m0 + row;
    if (permA == 1) ar = (ar & 127) * 384 + (ar >> 7);
    else if (permA == 2) ar = (ar % 384) * 128 + ar / 384;
    pA[q]  = A  + aoff + (long long)ar * lda + g * 8;
    pA2[q] = A2 + aoff + (long long)(m0 + row) * lda + g * 8;
    pB[q]  = B  + boff + (long long)(n0 + row) * ldbn + g * 8;
  }

  f32x4 acc[4][4] = {};
  int nkt = K >> 5;

  #pragma unroll
  for (int q = 0; q < 2; ++q) {
    gld16(pA[q], &SM[(w * 2 + q) * 512]);
    gld16(pB[q], &SM[8192 + (w * 2 + q) * 512]);
  }

  for (int t = 0; t < nkt; ++t) {
    int cur = t & 1;
    const u16* aC = &SM[cur * 4096];
    const u16* bC = &SM[8192 + cur * 4096];
    if (t + 1 < nkt) {
      int tn = t + 1;
      #pragma unroll
      for (int q = 0; q < 2; ++q) {
        const u16* srcA = (tn < ksplit) ? (pA[q] + (long long)tn * kasb)
                                        : (pA2[q] + (long long)(tn - ksplit) * kasb);
        gld16(srcA, &SM[(cur ^ 1) * 4096 + (w * 2 + q) * 512]);
        gld16(pB[q] + (long long)tn * kbsb, &SM[8192 + (cur ^ 1) * 4096 + (w * 2 + q) * 512]);
      }
      asm volatile("s_waitcnt vmcnt(4)" ::: "memory");
    } else {
      asm volatile("s_waitcnt vmcnt(0)" ::: "memory");
    }
    __builtin_amdgcn_sched_barrier(0);
    __builtin_amdgcn_s_barrier();
    __builtin_amdgcn_sched_barrier(0);
    bf16x8v af[4], bf[4];
    #pragma unroll
    for (int f = 0; f < 4; ++f) {
      int rowA = wm * 64 + f * 16 + (lane & 15);
      int cA = (lane >> 4) ^ ((rowA >> 1) & 3);
      af[f] = *(const bf16x8v*)&aC[rowA * 32 + cA * 8];
      int rowB = wn * 64 + f * 16 + (lane & 15);
      int cB = (lane >> 4) ^ ((rowB >> 1) & 3);
      bf[f] = *(const bf16x8v*)&bC[rowB * 32 + cB * 8];
    }
    __builtin_amdgcn_s_setprio(1);
    #pragma unroll
    for (int mt = 0; mt < 4; ++mt)
      #pragma unroll
      for (int nt = 0; nt < 4; ++nt)
        acc[mt][nt] = MFMA16(af[mt], bf[nt], acc[mt][nt]);
    __builtin_amdgcn_s_setprio(0);
    __builtin_amdgcn_sched_barrier(0);
    __builtin_amdgcn_s_barrier();
  }

  bool obf = flags & 1, beta = flags & 2, relu = flags & 4, atom = flags & 8, xad = flags & 16;
  float* Cf = (float*)Cv;
  u16* Cb = (u16*)Cv;
  if (obf) {
    u16* Cs = SM;  // 128x128 u16 = all 32KB
    #pragma unroll
    for (int mt = 0; mt < 4; ++mt)
      #pragma unroll
      for (int nt = 0; nt < 4; ++nt)
        #pragma unroll
        for (int rg = 0; rg < 4; ++rg) {
          int m = wm * 64 + mt * 16 + (lane >> 4) * 4 + rg;
          int n = wn * 64 + nt * 16 + (lane & 15);
          float v = alpha * acc[mt][nt][rg];
          if (bias) v += bias[n0 + n];
          if (relu) v = fmaxf(v, 0.f);
          Cs[m * 128 + n] = f2bf(v);
        }
    __builtin_amdgcn_s_barrier();
    #pragma unroll
    for (int q = 0; q < 8; ++q) {
      int slot = q * 256 + tid;
      int m = slot >> 4, ns = (slot & 15) * 8;
      int ng = n0 + ns;
      long long ci = coff + (long long)(m0 + m) * ldc + (long long)(ng >> 5) * cnsb + (ng & 31);
      *(uint4*)(Cb + ci) = *(const uint4*)&Cs[m * 128 + ns];
    }
  } else if (!beta && !atom) {
    // staged f32 epilogue: two 64-row halves, coalesced float4 stores (+ coalesced Xadd)
    float* Csf = (float*)SM;  // 64x128 f32 = 32KB
    #pragma unroll
    for (int half = 0; half < 2; ++half) {
      if (wm == half) {
        #pragma unroll
        for (int mt = 0; mt < 4; ++mt)
          #pragma unroll
          for (int nt = 0; nt < 4; ++nt)
            #pragma unroll
            for (int rg = 0; rg < 4; ++rg) {
              int m = mt * 16 + (lane >> 4) * 4 + rg;       // 0..63
              int n = wn * 64 + nt * 16 + (lane & 15);      // 0..127
              float v = alpha * acc[mt][nt][rg];
              if (bias) v += bias[n0 + n];
              if (relu) v = fmaxf(v, 0.f);
              Csf[m * 128 + n] = v;
            }
      }
      __builtin_amdgcn_s_barrier();
      #pragma unroll
      for (int q = 0; q < 8; ++q) {
        int slot = q * 256 + tid;                           // 0..2047
        int m = slot >> 5, f4 = slot & 31;
        int mg = m0 + half * 64 + m;
        int ng = n0 + f4 * 4;
        long long ci = coff + (long long)mg * ldc + (long long)(ng >> 5) * cnsb + (ng & 31);
        float4 v4 = *(float4*)&Csf[m * 128 + f4 * 4];
        if (xad) {
          float4 xv = *(const float4*)&Xadd[ci];
          v4.x += xv.x; v4.y += xv.y; v4.z += xv.z; v4.w += xv.w;
        }
        *(float4*)&Cf[ci] = v4;
      }
      __builtin_amdgcn_s_barrier();
    }
  } else {
    #pragma unroll
    for (int mt = 0; mt < 4; ++mt)
      #pragma unroll
      for (int nt = 0; nt < 4; ++nt)
        #pragma unroll
        for (int rg = 0; rg < 4; ++rg) {
          int m = m0 + wm * 64 + mt * 16 + (lane >> 4) * 4 + rg;
          int n = n0 + wn * 64 + nt * 16 + (lane & 15);
          float v = alpha * acc[mt][nt][rg];
          if (bias) v += bias[n];
          long long ci = coff + (long long)m * ldc + (long long)(n >> 5) * cnsb + (n & 31);
          if (atom) {
            atomicAdd(&Cf[ci], v);
          } else {
            if (beta) v += Cf[ci];
            if (relu) v = fmaxf(v, 0.f);
            Cf[ci] = v;
          }
        }
  }
}

// ---------------- FFN v6 (proven 89us): private HS, dbuf weights, counted vmcnt ----------------
__global__ __launch_bounds__(768, 3) void ffn_kernel(
    const u16* __restrict__ xn2,      // [RL][256] bf16
    const u16* __restrict__ w1t,      // [1024][256] bf16
    const float* __restrict__ b1,     // [1024]
    const u16* __restrict__ w2t,      // [256][1024] bf16
    const float* __restrict__ b2,     // [256]
    float* __restrict__ io) {         // d_out [RL][256] f32
  __shared__ __align__(16) u16 W1c[2][8192];
  __shared__ __align__(16) u16 W2c[2][8192];
  __shared__ __align__(16) u16 HSa[12 * 640];
  int tid = threadIdx.x, lane = tid & 63, w = tid >> 6;
  int m0 = blockIdx.x * 192 + w * 16;

  bf16x8v af[8];
  #pragma unroll
  for (int ksl = 0; ksl < 8; ++ksl)
    af[ksl] = *(const bf16x8v*)(xn2 + (size_t)(m0 + (lane & 15)) * 256 + ksl * 32 + (lane >> 4) * 8);

  u16* HS = HSa + w * 640;
  f32x4 acc2[16] = {};

  auto STAGE = [&](int c, int d) {
    if (w < 8) {
      #pragma unroll
      for (int q = 0; q < 4; ++q) {
        int o = w * 4 + q;
        if (o < 16) {
          int r = o * 2 + (lane >> 5);
          int g = lane & 31;
          int gs = (g & 24) | ((g & 7) ^ (r & 7));
          gld16(w1t + (size_t)(c * 32 + r) * 256 + gs * 8, &W1c[d][o * 512]);
        } else {
          int o2 = o - 16;
          int r = o2 * 16 + (lane >> 2);
          int gs = (lane & 3) ^ ((r >> 1) & 3);
          gld16(w2t + (size_t)r * 1024 + c * 32 + gs * 8, &W2c[d][o2 * 512]);
        }
      }
    }
  };

  STAGE(0, 0);
  __syncthreads();

  #pragma unroll 1
  for (int c = 0; c < 32; ++c) {
    int cur = c & 1;
    if (c + 1 < 32) {
      STAGE(c + 1, cur ^ 1);
      asm volatile("s_waitcnt vmcnt(4)" ::: "memory");
    } else {
      asm volatile("s_waitcnt vmcnt(0)" ::: "memory");
    }
    __builtin_amdgcn_sched_barrier(0);
    __builtin_amdgcn_s_barrier();
    __builtin_amdgcn_sched_barrier(0);

    f32x4 acc1[2] = {};
    #pragma unroll
    for (int ks = 0; ks < 8; ++ks) {
      #pragma unroll
      for (int nf = 0; nf < 2; ++nf) {
        int row = nf * 16 + (lane & 15);
        int cg = ks * 4 + (lane >> 4);
        int ch = (cg & 24) | ((cg & 7) ^ (row & 7));
        bf16x8v bf = *(const bf16x8v*)&W1c[cur][row * 256 + ch * 8];
        acc1[nf] = MFMA16(af[ks], bf, acc1[nf]);
      }
    }
    #pragma unroll
    for (int nf = 0; nf < 2; ++nf) {
      int col = nf * 16 + (lane & 15);
      float bias = b1[c * 32 + col];
      #pragma unroll
      for (int rg = 0; rg < 4; ++rg) {
        float v = fmaxf(acc1[nf][rg] + bias, 0.f);
        HS[((lane >> 4) * 4 + rg) * 40 + col] = f2bf(v);
      }
    }
    bf16x8v ahs = *(const bf16x8v*)&HS[(lane & 15) * 40 + (lane >> 4) * 8];
    __builtin_amdgcn_s_setprio(1);
    #pragma unroll
    for (int nf = 0; nf < 16; ++nf) {
      int n2 = nf * 16 + (lane & 15);
      int ch = (lane >> 4) ^ ((n2 >> 1) & 3);
      bf16x8v bf = *(const bf16x8v*)&W2c[cur][n2 * 32 + ch * 8];
      acc2[nf] = MFMA16(ahs, bf, acc2[nf]);
    }
    __builtin_amdgcn_s_setprio(0);
    __builtin_amdgcn_sched_barrier(0);
    __builtin_amdgcn_s_barrier();
  }

  #pragma unroll
  for (int nf = 0; nf < 16; ++nf) {
    int n = nf * 16 + (lane & 15);
    float bb = b2[n];
    #pragma unroll
    for (int rg = 0; rg < 4; ++rg) {
      int row = m0 + (lane >> 4) * 4 + rg;
      size_t ci = (size_t)row * 256 + n;
      io[ci] += acc2[nf][rg] + bb;
    }
  }
}

// ---------------- fused width attention (l-major proj): one block per (l, h) ----------------
__global__ __launch_bounds__(256) void wattn_kernel(const u16* __restrict__ proj,
                                                    u16* __restrict__ outc) {
  int l = blockIdx.x >> 3, h = blockIdx.x & 7;
  int tid = threadIdx.x, lane = tid & 63, w = tid >> 6;
  __shared__ u16 Pl[128][136];
  __shared__ u16 Vl[128][40];
  {
    int r = tid >> 1, dh0 = (tid & 1) * 16;
    const u16* src = proj + ((size_t)(l * R_ + r)) * 768 + 512 + h * 32 + dh0;
    *(uint4*)&Vl[r][dh0] = *(const uint4*)src;
    *(uint4*)&Vl[r][dh0 + 8] = *(const uint4*)(src + 8);
  }
  f32x4 s[2][8] = {};
  bf16x8v qf[2];
  #pragma unroll
  for (int mt = 0; mt < 2; ++mt) {
    int row = w * 32 + mt * 16 + (lane & 15);
    qf[mt] = *(const bf16x8v*)(proj + ((size_t)(l * R_ + row)) * 768 + h * 32 + (lane >> 4) * 8);
  }
  #pragma unroll
  for (int ct = 0; ct < 8; ++ct) {
    int col = ct * 16 + (lane & 15);
    bf16x8v kf = *(const bf16x8v*)(proj + ((size_t)(l * R_ + col)) * 768 + 256 + h * 32 + (lane >> 4) * 8);
    s[0][ct] = MFMA16(qf[0], kf, s[0][ct]);
    s[1][ct] = MFMA16(qf[1], kf, s[1][ct]);
  }
  const float scale = 0.1767766952966369f;  // 32^-0.5
  #pragma unroll
  for (int mt = 0; mt < 2; ++mt)
    #pragma unroll
    for (int rg = 0; rg < 4; ++rg) {
      float mx = -1e30f;
      #pragma unroll
      for (int ct = 0; ct < 8; ++ct) { s[mt][ct][rg] *= scale; mx = fmaxf(mx, s[mt][ct][rg]); }
      #pragma unroll
      for (int off = 1; off < 16; off <<= 1) mx = fmaxf(mx, __shfl_xor(mx, off));
      float sum = 0.f;
      #pragma unroll
      for (int ct = 0; ct < 8; ++ct) { float pv = __expf(s[mt][ct][rg] - mx); s[mt][ct][rg] = pv; sum += pv; }
      #pragma unroll
      for (int off = 1; off < 16; off <<= 1) sum += __shfl_xor(sum, off);
      float inv = 1.f / sum;
      int row = w * 32 + mt * 16 + (lane >> 4) * 4 + rg;
      #pragma unroll
      for (int ct = 0; ct < 8; ++ct) Pl[row][ct * 16 + (lane & 15)] = f2bf(s[mt][ct][rg] * inv);
    }
  __syncthreads();
  f32x4 o[2][2] = {};
  #pragma unroll
  for (int kk = 0; kk < 4; ++kk) {
    bf16x8v pa[2];
    #pragma unroll
    for (int mt = 0; mt < 2; ++mt)
      pa[mt] = *(const bf16x8v*)&Pl[w * 32 + mt * 16 + (lane & 15)][kk * 32 + (lane >> 4) * 8];
    #pragma unroll
    for (int nt = 0; nt < 2; ++nt) {
      bf16x8v vb;
      #pragma unroll
      for (int e = 0; e < 8; ++e) vb[e] = (short)Vl[kk * 32 + (lane >> 4) * 8 + e][nt * 16 + (lane & 15)];
      o[0][nt] = MFMA16(pa[0], vb, o[0][nt]);
      o[1][nt] = MFMA16(pa[1], vb, o[1][nt]);
    }
  }
  #pragma unroll
  for (int mt = 0; mt < 2; ++mt)
    #pragma unroll
    for (int nt = 0; nt < 2; ++nt)
      #pragma unroll
      for (int rg = 0; rg < 4; ++rg) {
        int row = w * 32 + mt * 16 + (lane >> 4) * 4 + rg;
        int dh = nt * 16 + (lane & 15);
        outc[((size_t)(l * R_ + row)) * 256 + h * 32 + dh] = f2bf(o[mt][nt][rg]);
      }
}

// ---------------- fused pair-bias LN + height softmax: one block per i ----------------
__global__ __launch_bounds__(512) void pairsm_kernel(const float* __restrict__ pair,
                                                     const float* __restrict__ wprime,
                                                     const float* __restrict__ wc,
                                                     const float* __restrict__ dots,
                                                     u16* __restrict__ attn) {
  int i = blockIdx.x;
  int tid = threadIdx.x, lane = tid & 63, w = tid >> 6;
  __shared__ float bias_s[384][9];
  int sub = lane & 15, g = lane >> 4;

  float4 wv[16];
  #pragma unroll
  for (int c = 0; c < 8; ++c) {
    wv[c * 2]     = *(const float4*)(wprime + (sub * 8 + c) * 8);
    wv[c * 2 + 1] = *(const float4*)(wprime + (sub * 8 + c) * 8 + 4);
  }

  #pragma unroll 1
  for (int pass = 0; pass < 12; ++pass) {
    int j = pass * 32 + w * 4 + g;
    const float* px = pair + ((size_t)i * L_ + j) * 128 + sub * 8;
    float4 a = *(const float4*)px;
    float4 b = *(const float4*)(px + 4);
    float xa[8] = {a.x, a.y, a.z, a.w, b.x, b.y, b.z, b.w};
    float s1 = 0.f, s2 = 0.f;
    float t0 = 0, t1 = 0, t2 = 0, t3 = 0, t4 = 0, t5 = 0, t6 = 0, t7 = 0;
    #pragma unroll
    for (int c = 0; c < 8; ++c) {
      float xv = xa[c];
      s1 += xv; s2 += xv * xv;
      t0 += wv[c * 2].x * xv; t1 += wv[c * 2].y * xv;
      t2 += wv[c * 2].z * xv; t3 += wv[c * 2].w * xv;
      t4 += wv[c * 2 + 1].x * xv; t5 += wv[c * 2 + 1].y * xv;
      t6 += wv[c * 2 + 1].z * xv; t7 += wv[c * 2 + 1].w * xv;
    }
    #pragma unroll
    for (int off = 1; off < 16; off <<= 1) {
      s1 += __shfl_xor(s1, off); s2 += __shfl_xor(s2, off);
      t0 += __shfl_xor(t0, off); t1 += __shfl_xor(t1, off);
      t2 += __shfl_xor(t2, off); t3 += __shfl_xor(t3, off);
      t4 += __shfl_xor(t4, off); t5 += __shfl_xor(t5, off);
      t6 += __shfl_xor(t6, off); t7 += __shfl_xor(t7, off);
    }
    if (sub < 8) {
      float mu = s1 * (1.f / 128.f);
      float rstd = rsqrtf(s2 * (1.f / 128.f) - mu * mu + 1e-5f);
      float tv = t0;
      if (sub == 1) tv = t1; if (sub == 2) tv = t2; if (sub == 3) tv = t3;
      if (sub == 4) tv = t4; if (sub == 5) tv = t5; if (sub == 6) tv = t6;
      if (sub == 7) tv = t7;
      bias_s[j][sub] = rstd * (tv - mu * wc[sub]) + wc[8 + sub];
    }
  }
  __syncthreads();

  int h = w;
  const float* dr = dots + ((size_t)h * L_ + i) * L_;
  float v[6];
  #pragma unroll
  for (int u = 0; u < 6; ++u) v[u] = dr[lane + u * 64] + bias_s[lane + u * 64][h];
  float mx = v[0];
  #pragma unroll
  for (int u = 1; u < 6; ++u) mx = fmaxf(mx, v[u]);
  #pragma unroll
  for (int off = 1; off < 64; off <<= 1) mx = fmaxf(mx, __shfl_xor(mx, off));
  float s = 0.f;
  #pragma unroll
  for (int u = 0; u < 6; ++u) { v[u] = __expf(v[u] - mx); s += v[u]; }
  #pragma unroll
  for (int off = 1; off < 64; off <<= 1) s += __shfl_xor(s, off);
  float inv = 1.f / s;
  #pragma unroll
  for (int u = 0; u < 6; ++u)
    attn[((size_t)h * L_ + i) * L_ + lane + u * 64] = f2bf(v[u] * inv);
}

// ---------------- V transpose for height: vt[(h*128+r)*32+d][j] = v[r,h,j,d] ----------------
__global__ __launch_bounds__(256) void vt_kernel(const u16* __restrict__ proj,
                                                 u16* __restrict__ vt) {
  int bz = blockIdx.x;
  int jc = bz % 6, hr = bz / 6;
  int h = hr >> 7, r = hr & 127;
  int j0 = jc * 64;
  __shared__ u16 T[64][40];
  int t = threadIdx.x;
  {
    int jr = t >> 2, seg = t & 3;
    *(uint4*)&T[jr][seg * 8] =
        *(const uint4*)(proj + ((size_t)(r * L_ + j0 + jr)) * 768 + 512 + h * 32 + seg * 8);
  }
  __syncthreads();
  {
    int dr = t >> 3, sg = t & 7;
    u16 tmp[8];
    #pragma unroll
    for (int u = 0; u < 8; ++u) tmp[u] = T[sg * 8 + u][dr];
    uint4 pk;
    pk.x = (unsigned)tmp[0] | ((unsigned)tmp[1] << 16);
    pk.y = (unsigned)tmp[2] | ((unsigned)tmp[3] << 16);
    pk.z = (unsigned)tmp[4] | ((unsigned)tmp[5] << 16);
    pk.w = (unsigned)tmp[6] | ((unsigned)tmp[7] << 16);
    *(uint4*)(vt + ((size_t)hr * 32 + dr) * 384 + j0 + sg * 8) = pk;
  }
}

// =====================================================================
extern "C" void kernel_launch(void* const* d_in, const int* in_sizes, int n_in,
                              void* d_out, int out_size, void* d_ws, size_t ws_size,
                              hipStream_t stream) {
  const float* x      = (const float*)d_in[0];
  const float* pair   = (const float*)d_in[1];
  const float* ln1_g  = (const float*)d_in[2];
  const float* ln1_b  = (const float*)d_in[3];
  const float* wq_w   = (const float*)d_in[4];
  const float* wkv_w  = (const float*)d_in[5];
  const float* wout_w = (const float*)d_in[6];
  const float* wout_b = (const float*)d_in[7];
  const float* hq_w   = (const float*)d_in[8];
  const float* hkv_w  = (const float*)d_in[9];
  const float* hout_w = (const float*)d_in[10];
  const float* hout_b = (const float*)d_in[11];
  const float* pn_g   = (const float*)d_in[12];
  const float* pn_b   = (const float*)d_in[13];
  const float* pl_w   = (const float*)d_in[14];
  const float* ln2_g  = (const float*)d_in[15];
  const float* ln2_b  = (const float*)d_in[16];
  const float* ff_w1  = (const float*)d_in[17];
  const float* ff_b1  = (const float*)d_in[18];
  const float* ff_w2  = (const float*)d_in[19];
  const float* ff_b2  = (const float*)d_in[20];

  char* ws = (char*)d_ws;
  u16* xnA   = (u16*)(ws + A_OFF);
  u16* projB = (u16*)(ws + B_OFF);
  u16* hattB = (u16*)(ws + B_OFF);
  u16* attC  = (u16*)(ws + C_OFF);
  float* dotsD = (float*)(ws + D_OFF);
  u16* attnF = (u16*)(ws + F_OFF);
  u16* wqkvT_w = (u16*)(ws + EW_W);
  u16* wqkvT_h = (u16*)(ws + EW_H);
  u16* oT    = (u16*)(ws + EW_OT);
  u16* ff1T  = (u16*)(ws + EW_FF1);
  u16* ff2T  = (u16*)(ws + EW_FF2);
  float* wprime = (float*)(ws + EW_WP);
  float* wc     = (float*)(ws + EW_WC);
  float* bsum   = (float*)(ws + EW_BS);
  float* outF = (float*)d_out;
  constexpr int KBIG = 1 << 30;

  // --- single batched prep launch: all transposes + pairprep ---
  prep_kernel<<<dim3(4097), dim3(256), 0, stream>>>(
      wq_w, wkv_w, hq_w, hkv_w, ff_w1, ff_w2, wout_w, hout_w,
      wqkvT_w, wqkvT_h, ff1T, ff2T, oT,
      pn_g, pn_b, pl_w, wout_b, hout_b, wprime, wc, bsum);

  hipMemsetAsync(dotsD, 0, (size_t)H_ * L_ * L_ * 4, stream);

  // --- LN1 ---
  ln1_kernel<<<dim3(RL_ / 4), dim3(256), 0, stream>>>(x, ln1_g, ln1_b, xnA);

  // --- width projection (l-major output): grid (ntile=6, mtile=384) ---
  gemm128_kernel<<<dim3(6, 384, 1), dim3(256), 0, stream>>>(
      xnA, xnA, wqkvT_w, projB, nullptr, nullptr, RL_, 768, 256,
      256, 32LL, 256, 32LL, 768, 32LL, 0LL, 0LL, 0LL, KBIG, 1 /*permA: l-major*/,
      1, 0LL, 0LL, 0LL, 0LL, 0LL, 0LL, 1.f, 1 /*bf16*/);

  // --- width fused attention (l-major in/out) -> attC ---
  wattn_kernel<<<dim3(L_ * H_), dim3(256), 0, stream>>>(projB, attC);

  // --- height projection: grid (6, 384) ---
  gemm128_kernel<<<dim3(6, 384, 1), dim3(256), 0, stream>>>(
      xnA, xnA, wqkvT_h, projB, nullptr, nullptr, RL_, 768, 256,
      256, 32LL, 256, 32LL, 768, 32LL, 0LL, 0LL, 0LL, KBIG, 0,
      1, 0LL, 0LL, 0LL, 0LL, 0LL, 0LL, 1.f, 1);

  // --- height dots: per head, split-K x4, atomic accumulate; grid (ntile=3, mtile=3, 32) ---
  gemm128_kernel<<<dim3(3, 3, 32), dim3(256), 0, stream>>>(
      projB, projB, projB, dotsD, nullptr, nullptr, 384, 384, 1024,
      768, (long long)L_ * 768, 768, (long long)L_ * 768, 384, 32LL,
      0LL, 256LL, 0LL, KBIG, 0,
      4, 32LL, 32LL * L_ * 768, 32LL, 32LL * L_ * 768,
      (long long)L_ * L_, 0LL, 1.f / 64.f, 8 /*atomic*/);

  // --- fused pair-bias LN + height softmax -> attn bf16 ---
  pairsm_kernel<<<dim3(L_), dim3(512), 0, stream>>>(pair, wprime, wc, dotsD, attnF);

  // --- V transpose (into A region; xn no longer needed) ---
  vt_kernel<<<dim3(H_ * R_ * 6), dim3(256), 0, stream>>>(projB, xnA);

  // --- ho: per head; grid (ntile=32, mtile=3, 8) ---
  gemm128_kernel<<<dim3(32, 3, 8), dim3(256), 0, stream>>>(
      attnF, attnF, xnA, hattB, nullptr, nullptr, 384, 4096, 384,
      384, 32LL, 384, 32LL, 256, (long long)L_ * 256,
      0LL, 0LL, 0LL, KBIG, 0,
      8, 0LL, (long long)L_ * L_, 0LL, 1572864LL, 0LL, 32LL, 1.f, 1 /*bf16*/);

  // --- fused out-proj + residual (staged, coalesced); grid (ntile=2, mtile=384) ---
  gemm128_kernel<<<dim3(2, 384, 1), dim3(256), 0, stream>>>(
      attC, hattB, oT, outF, bsum, x, RL_, 256, 512,
      256, 32LL, 512, 32LL, 256, 32LL, 0LL, 0LL, 0LL, 8 /*ksplit*/, 2 /*permA*/,
      1, 0LL, 0LL, 0LL, 0LL, 0LL, 0LL, 0.5f, 16 /*xadd*/);

  // --- LN2 -> xn2 (A region) ---
  ln1_kernel<<<dim3(RL_ / 4), dim3(256), 0, stream>>>(outF, ln2_g, ln2_b, xnA);

  // --- FFN v6: d_out += relu(xn2@W1+b1)@W2 + b2 ---
  ffn_kernel<<<dim3(256), dim3(768), 0, stream>>>(
      xnA, ff1T, ff_b1, ff2T, ff_b2, outF);
}

// Round 17
// 429.826 us; speedup vs baseline: 1.0151x; 1.0151x over previous
//
#include <hip/hip_runtime.h>

typedef float f32x4 __attribute__((ext_vector_type(4)));
typedef short bf16x8v __attribute__((ext_vector_type(8)));
typedef unsigned short u16;
typedef unsigned int u32;

#define DEVI static __device__ __forceinline__

constexpr int R_ = 128, L_ = 384, D_ = 256, H_ = 8;
constexpr int RL_ = R_ * L_;          // 49152

// ---- ws byte offsets ----
constexpr size_t A_OFF = 0;                    // 25,165,824  xn bf16 / vt / xn2
constexpr size_t B_OFF = 25165824;             // 75,497,472  proj bf16 / height attn out
constexpr size_t C_OFF = 100663296;            // 25,165,824  width attn out bf16 (l-major)
constexpr size_t D_OFF = 125829120;            //  4,718,592  height dots f32
constexpr size_t F_OFF = 130547712;            //  2,359,296  height attn bf16
constexpr size_t EW_W    = 132907008;          // wqkv^T bf16 [768][256]
constexpr size_t EW_H    = 133300224;          // hqkv^T bf16 [768][256]
constexpr size_t EW_OT   = 133693440;          // oT bf16 [256][512]
constexpr size_t EW_FF1  = 133955584;          // ff1^T bf16 [1024][256]
constexpr size_t EW_FF2  = 134479872;          // ff2^T bf16 [256][1024]
constexpr size_t EW_WP   = 135004160;          // w' f32 [128][8]
constexpr size_t EW_WC   = 135008256;          // W[8],C[8] f32
constexpr size_t EW_BS   = 135008320;          // wout_b+hout_b f32 [256]

DEVI u16 f2bf(float f) {
  unsigned int b = __builtin_bit_cast(unsigned int, f);
  b += 0x7FFFu + ((b >> 16) & 1u);
  return (u16)(b >> 16);
}

#define MFMA16(a, b, c) __builtin_amdgcn_mfma_f32_16x16x32_bf16(a, b, c, 0, 0, 0)

typedef __attribute__((address_space(3))) u32 lds_u32;
typedef const __attribute__((address_space(1))) u32 glb_u32;
DEVI void gld16(const void* g, void* l) {
  __builtin_amdgcn_global_load_lds((glb_u32*)g, (lds_u32*)l, 16, 0, 0);
}

// ---------------- batched prep: all weight transposes + pair-bias prep, ONE launch ----------
// blocks [0,4096): transposes; block 4096: pairprep.
__global__ __launch_bounds__(256) void prep_kernel(
    const float* __restrict__ wq, const float* __restrict__ wkv,
    const float* __restrict__ hq, const float* __restrict__ hkv,
    const float* __restrict__ ff1, const float* __restrict__ ff2,
    const float* __restrict__ wout, const float* __restrict__ hout,
    u16* __restrict__ wT_w, u16* __restrict__ wT_h,
    u16* __restrict__ f1T, u16* __restrict__ f2T, u16* __restrict__ oT,
    const float* __restrict__ png, const float* __restrict__ pnb,
    const float* __restrict__ plw,
    const float* __restrict__ woutb, const float* __restrict__ houtb,
    float* __restrict__ wprime, float* __restrict__ wc, float* __restrict__ bsum) {
  int b = blockIdx.x;
  if (b < 4096) {
    const float* src; u16* dst; int N, dstK, koff, base;
    if (b < 256)       { src = wq;   dst = wT_w;          N = 256;  dstK = 256;  koff = 0;   base = 0; }
    else if (b < 768)  { src = wkv;  dst = wT_w + 65536;  N = 512;  dstK = 256;  koff = 0;   base = 256; }
    else if (b < 1024) { src = hq;   dst = wT_h;          N = 256;  dstK = 256;  koff = 0;   base = 768; }
    else if (b < 1536) { src = hkv;  dst = wT_h + 65536;  N = 512;  dstK = 256;  koff = 0;   base = 1024; }
    else if (b < 2560) { src = ff1;  dst = f1T;           N = 1024; dstK = 256;  koff = 0;   base = 1536; }
    else if (b < 3584) { src = ff2;  dst = f2T;           N = 256;  dstK = 1024; koff = 0;   base = 2560; }
    else if (b < 3840) { src = wout; dst = oT;            N = 256;  dstK = 512;  koff = 0;   base = 3584; }
    else               { src = hout; dst = oT;            N = 256;  dstK = 512;  koff = 256; base = 3840; }
    int idx = (b - base) * 256 + threadIdx.x;
    int k = idx / N, n = idx - k * N;
    dst[(size_t)n * dstK + koff + k] = f2bf(src[idx]);
  } else {
    int p = threadIdx.x;
    if (p < 128) {
      float g = png[p];
      #pragma unroll
      for (int h = 0; h < 8; ++h) wprime[p * 8 + h] = g * plw[p * 8 + h];
      bsum[p] = woutb[p] + houtb[p];
      bsum[p + 128] = woutb[p + 128] + houtb[p + 128];
    }
    if (p == 0) {
      for (int h = 0; h < 8; ++h) {
        float W = 0.f, C = 0.f;
        for (int q = 0; q < 128; ++q) { W += png[q] * plw[q * 8 + h]; C += pnb[q] * plw[q * 8 + h]; }
        wc[h] = W; wc[8 + h] = C;
      }
    }
  }
}

// ---------------- LN over 256 channels, one wave per row ----------------
DEVI void ln_store(float4 v, const float* __restrict__ g, const float* __restrict__ b,
                   u16* __restrict__ dst, int lane) {
  float s1 = v.x + v.y + v.z + v.w;
  float s2 = v.x * v.x + v.y * v.y + v.z * v.z + v.w * v.w;
  #pragma unroll
  for (int off = 1; off < 64; off <<= 1) { s1 += __shfl_xor(s1, off); s2 += __shfl_xor(s2, off); }
  float mu = s1 * (1.f / 256.f);
  float rstd = rsqrtf(s2 * (1.f / 256.f) - mu * mu + 1e-5f);
  float4 gg = *(const float4*)(g + lane * 4);
  float4 bb = *(const float4*)(b + lane * 4);
  ushort4 o = make_ushort4(f2bf((v.x - mu) * rstd * gg.x + bb.x),
                           f2bf((v.y - mu) * rstd * gg.y + bb.y),
                           f2bf((v.z - mu) * rstd * gg.z + bb.z),
                           f2bf((v.w - mu) * rstd * gg.w + bb.w));
  *(ushort4*)dst = o;
}

__global__ __launch_bounds__(256) void ln1_kernel(const float* __restrict__ x,
                                                  const float* __restrict__ g,
                                                  const float* __restrict__ b,
                                                  u16* __restrict__ out) {
  int wid = (blockIdx.x * 256 + threadIdx.x) >> 6;
  if (wid >= RL_) return;
  int lane = threadIdx.x & 63;
  float4 v = *(const float4*)(x + (size_t)wid * 256 + lane * 4);
  ln_store(v, g, b, out + (size_t)wid * 256 + lane * 4, lane);
}

// residual: io = x + 0.5*io ; out = bf16(LN(io))
__global__ __launch_bounds__(256) void resln_kernel(const float* __restrict__ x,
                                                    float* __restrict__ io,
                                                    const float* __restrict__ g,
                                                    const float* __restrict__ b,
                                                    u16* __restrict__ out) {
  int wid = (blockIdx.x * 256 + threadIdx.x) >> 6;
  if (wid >= RL_) return;
  int lane = threadIdx.x & 63;
  size_t base = (size_t)wid * 256 + lane * 4;
  float4 xv = *(const float4*)(x + base);
  float4 ov = *(const float4*)(io + base);
  float4 nv = make_float4(xv.x + 0.5f * ov.x, xv.y + 0.5f * ov.y,
                          xv.z + 0.5f * ov.z, xv.w + 0.5f * ov.w);
  *(float4*)(io + base) = nv;
  ln_store(nv, g, b, out + base, lane);
}

// ---------------- gemm128: BK=32, dbuf LDS (32KB), counted vmcnt, split-A, A-row perm ---
// permA: 0=identity, 1: phys=(row&127)*384+(row>>7), 2: phys=(row%384)*128+row/384
// flags: 1=out bf16 (LDS-staged), 2=beta f32, 4=relu, 8=atomicAdd f32
__global__ __launch_bounds__(256) void gemm128_kernel(
    const u16* __restrict__ A, const u16* __restrict__ A2, const u16* __restrict__ B,
    void* __restrict__ Cv, const float* __restrict__ bias,
    int M, int N, int K,
    int lda, long long kasb, int ldbn, long long kbsb, int ldc, long long cnsb,
    long long abase, long long bbase, long long cbase, int ksplit, int permA,
    int Z2, long long as1, long long as2, long long bs1, long long bs2,
    long long cs1, long long cs2,
    float alpha, int flags) {
  __shared__ __align__(16) u16 SM[16384];
  int z = blockIdx.z, z1 = z / Z2, z2 = z - z1 * Z2;
  long long aoff = abase + z1 * as1 + z2 * as2;
  long long boff = bbase + z1 * bs1 + z2 * bs2;
  long long coff = cbase + z1 * cs1 + z2 * cs2;
  int m0 = blockIdx.x * 128, n0 = blockIdx.y * 128;
  int tid = threadIdx.x, lane = tid & 63, w = tid >> 6;
  int wm = w >> 1, wn = w & 1;

  const u16* pA[2]; const u16* pA2[2]; const u16* pB[2];
  #pragma unroll
  for (int q = 0; q < 2; ++q) {
    int row = (w * 2 + q) * 16 + (lane >> 2);
    int g = (lane & 3) ^ ((row >> 1) & 3);
    int ar = m0 + row;
    if (permA == 1) ar = (ar & 127) * 384 + (ar >> 7);
    else if (permA == 2) ar = (ar % 384) * 128 + ar / 384;
    pA[q]  = A  + aoff + (long long)ar * lda + g * 8;
    pA2[q] = A2 + aoff + (long long)(m0 + row) * lda + g * 8;
    pB[q]  = B  + boff + (long long)(n0 + row) * ldbn + g * 8;
  }

  f32x4 acc[4][4] = {};
  int nkt = K >> 5;

  #pragma unroll
  for (int q = 0; q < 2; ++q) {
    gld16(pA[q], &SM[(w * 2 + q) * 512]);
    gld16(pB[q], &SM[8192 + (w * 2 + q) * 512]);
  }

  for (int t = 0; t < nkt; ++t) {
    int cur = t & 1;
    const u16* aC = &SM[cur * 4096];
    const u16* bC = &SM[8192 + cur * 4096];
    if (t + 1 < nkt) {
      int tn = t + 1;
      #pragma unroll
      for (int q = 0; q < 2; ++q) {
        const u16* srcA = (tn < ksplit) ? (pA[q] + (long long)tn * kasb)
                                        : (pA2[q] + (long long)(tn - ksplit) * kasb);
        gld16(srcA, &SM[(cur ^ 1) * 4096 + (w * 2 + q) * 512]);
        gld16(pB[q] + (long long)tn * kbsb, &SM[8192 + (cur ^ 1) * 4096 + (w * 2 + q) * 512]);
      }
      asm volatile("s_waitcnt vmcnt(4)" ::: "memory");
    } else {
      asm volatile("s_waitcnt vmcnt(0)" ::: "memory");
    }
    __builtin_amdgcn_sched_barrier(0);
    __builtin_amdgcn_s_barrier();
    __builtin_amdgcn_sched_barrier(0);
    bf16x8v af[4], bf[4];
    #pragma unroll
    for (int f = 0; f < 4; ++f) {
      int rowA = wm * 64 + f * 16 + (lane & 15);
      int cA = (lane >> 4) ^ ((rowA >> 1) & 3);
      af[f] = *(const bf16x8v*)&aC[rowA * 32 + cA * 8];
      int rowB = wn * 64 + f * 16 + (lane & 15);
      int cB = (lane >> 4) ^ ((rowB >> 1) & 3);
      bf[f] = *(const bf16x8v*)&bC[rowB * 32 + cB * 8];
    }
    __builtin_amdgcn_s_setprio(1);
    #pragma unroll
    for (int mt = 0; mt < 4; ++mt)
      #pragma unroll
      for (int nt = 0; nt < 4; ++nt)
        acc[mt][nt] = MFMA16(af[mt], bf[nt], acc[mt][nt]);
    __builtin_amdgcn_s_setprio(0);
    __builtin_amdgcn_sched_barrier(0);
    __builtin_amdgcn_s_barrier();
  }

  bool obf = flags & 1, beta = flags & 2, relu = flags & 4, atom = flags & 8;
  float* Cf = (float*)Cv;
  u16* Cb = (u16*)Cv;
  if (obf) {
    u16* Cs = SM;  // 128x128 u16 = all 32KB
    #pragma unroll
    for (int mt = 0; mt < 4; ++mt)
      #pragma unroll
      for (int nt = 0; nt < 4; ++nt)
        #pragma unroll
        for (int rg = 0; rg < 4; ++rg) {
          int m = wm * 64 + mt * 16 + (lane >> 4) * 4 + rg;
          int n = wn * 64 + nt * 16 + (lane & 15);
          float v = alpha * acc[mt][nt][rg];
          if (bias) v += bias[n0 + n];
          if (relu) v = fmaxf(v, 0.f);
          Cs[m * 128 + n] = f2bf(v);
        }
    __builtin_amdgcn_s_barrier();
    #pragma unroll
    for (int q = 0; q < 8; ++q) {
      int slot = q * 256 + tid;
      int m = slot >> 4, ns = (slot & 15) * 8;
      int ng = n0 + ns;
      long long ci = coff + (long long)(m0 + m) * ldc + (long long)(ng >> 5) * cnsb + (ng & 31);
      *(uint4*)(Cb + ci) = *(const uint4*)&Cs[m * 128 + ns];
    }
  } else {
    #pragma unroll
    for (int mt = 0; mt < 4; ++mt)
      #pragma unroll
      for (int nt = 0; nt < 4; ++nt)
        #pragma unroll
        for (int rg = 0; rg < 4; ++rg) {
          int m = m0 + wm * 64 + mt * 16 + (lane >> 4) * 4 + rg;
          int n = n0 + wn * 64 + nt * 16 + (lane & 15);
          float v = alpha * acc[mt][nt][rg];
          if (bias) v += bias[n];
          long long ci = coff + (long long)m * ldc + (long long)(n >> 5) * cnsb + (n & 31);
          if (atom) {
            atomicAdd(&Cf[ci], v);
          } else {
            if (beta) v += Cf[ci];
            if (relu) v = fmaxf(v, 0.f);
            Cf[ci] = v;
          }
        }
  }
}

// ---------------- FFN v6 (proven 89us): private HS, dbuf weights, counted vmcnt ----------------
__global__ __launch_bounds__(768, 3) void ffn_kernel(
    const u16* __restrict__ xn2,      // [RL][256] bf16
    const u16* __restrict__ w1t,      // [1024][256] bf16
    const float* __restrict__ b1,     // [1024]
    const u16* __restrict__ w2t,      // [256][1024] bf16
    const float* __restrict__ b2,     // [256]
    float* __restrict__ io) {         // d_out [RL][256] f32
  __shared__ __align__(16) u16 W1c[2][8192];
  __shared__ __align__(16) u16 W2c[2][8192];
  __shared__ __align__(16) u16 HSa[12 * 640];
  int tid = threadIdx.x, lane = tid & 63, w = tid >> 6;
  int m0 = blockIdx.x * 192 + w * 16;

  bf16x8v af[8];
  #pragma unroll
  for (int ksl = 0; ksl < 8; ++ksl)
    af[ksl] = *(const bf16x8v*)(xn2 + (size_t)(m0 + (lane & 15)) * 256 + ksl * 32 + (lane >> 4) * 8);

  u16* HS = HSa + w * 640;
  f32x4 acc2[16] = {};

  auto STAGE = [&](int c, int d) {
    if (w < 8) {
      #pragma unroll
      for (int q = 0; q < 4; ++q) {
        int o = w * 4 + q;
        if (o < 16) {
          int r = o * 2 + (lane >> 5);
          int g = lane & 31;
          int gs = (g & 24) | ((g & 7) ^ (r & 7));
          gld16(w1t + (size_t)(c * 32 + r) * 256 + gs * 8, &W1c[d][o * 512]);
        } else {
          int o2 = o - 16;
          int r = o2 * 16 + (lane >> 2);
          int gs = (lane & 3) ^ ((r >> 1) & 3);
          gld16(w2t + (size_t)r * 1024 + c * 32 + gs * 8, &W2c[d][o2 * 512]);
        }
      }
    }
  };

  STAGE(0, 0);
  __syncthreads();

  #pragma unroll 1
  for (int c = 0; c < 32; ++c) {
    int cur = c & 1;
    if (c + 1 < 32) {
      STAGE(c + 1, cur ^ 1);
      asm volatile("s_waitcnt vmcnt(4)" ::: "memory");
    } else {
      asm volatile("s_waitcnt vmcnt(0)" ::: "memory");
    }
    __builtin_amdgcn_sched_barrier(0);
    __builtin_amdgcn_s_barrier();
    __builtin_amdgcn_sched_barrier(0);

    f32x4 acc1[2] = {};
    #pragma unroll
    for (int ks = 0; ks < 8; ++ks) {
      #pragma unroll
      for (int nf = 0; nf < 2; ++nf) {
        int row = nf * 16 + (lane & 15);
        int cg = ks * 4 + (lane >> 4);
        int ch = (cg & 24) | ((cg & 7) ^ (row & 7));
        bf16x8v bf = *(const bf16x8v*)&W1c[cur][row * 256 + ch * 8];
        acc1[nf] = MFMA16(af[ks], bf, acc1[nf]);
      }
    }
    #pragma unroll
    for (int nf = 0; nf < 2; ++nf) {
      int col = nf * 16 + (lane & 15);
      float bias = b1[c * 32 + col];
      #pragma unroll
      for (int rg = 0; rg < 4; ++rg) {
        float v = fmaxf(acc1[nf][rg] + bias, 0.f);
        HS[((lane >> 4) * 4 + rg) * 40 + col] = f2bf(v);
      }
    }
    bf16x8v ahs = *(const bf16x8v*)&HS[(lane & 15) * 40 + (lane >> 4) * 8];
    __builtin_amdgcn_s_setprio(1);
    #pragma unroll
    for (int nf = 0; nf < 16; ++nf) {
      int n2 = nf * 16 + (lane & 15);
      int ch = (lane >> 4) ^ ((n2 >> 1) & 3);
      bf16x8v bf = *(const bf16x8v*)&W2c[cur][n2 * 32 + ch * 8];
      acc2[nf] = MFMA16(ahs, bf, acc2[nf]);
    }
    __builtin_amdgcn_s_setprio(0);
    __builtin_amdgcn_sched_barrier(0);
    __builtin_amdgcn_s_barrier();
  }

  #pragma unroll
  for (int nf = 0; nf < 16; ++nf) {
    int n = nf * 16 + (lane & 15);
    float bb = b2[n];
    #pragma unroll
    for (int rg = 0; rg < 4; ++rg) {
      int row = m0 + (lane >> 4) * 4 + rg;
      size_t ci = (size_t)row * 256 + n;
      io[ci] += acc2[nf][rg] + bb;
    }
  }
}

// ---------------- fused width attention (l-major proj): one block per (l, h) ----------------
__global__ __launch_bounds__(256) void wattn_kernel(const u16* __restrict__ proj,
                                                    u16* __restrict__ outc) {
  int l = blockIdx.x >> 3, h = blockIdx.x & 7;
  int tid = threadIdx.x, lane = tid & 63, w = tid >> 6;
  __shared__ u16 Pl[128][136];
  __shared__ u16 Vl[128][40];
  {
    int r = tid >> 1, dh0 = (tid & 1) * 16;
    const u16* src = proj + ((size_t)(l * R_ + r)) * 768 + 512 + h * 32 + dh0;
    *(uint4*)&Vl[r][dh0] = *(const uint4*)src;
    *(uint4*)&Vl[r][dh0 + 8] = *(const uint4*)(src + 8);
  }
  f32x4 s[2][8] = {};
  bf16x8v qf[2];
  #pragma unroll
  for (int mt = 0; mt < 2; ++mt) {
    int row = w * 32 + mt * 16 + (lane & 15);
    qf[mt] = *(const bf16x8v*)(proj + ((size_t)(l * R_ + row)) * 768 + h * 32 + (lane >> 4) * 8);
  }
  #pragma unroll
  for (int ct = 0; ct < 8; ++ct) {
    int col = ct * 16 + (lane & 15);
    bf16x8v kf = *(const bf16x8v*)(proj + ((size_t)(l * R_ + col)) * 768 + 256 + h * 32 + (lane >> 4) * 8);
    s[0][ct] = MFMA16(qf[0], kf, s[0][ct]);
    s[1][ct] = MFMA16(qf[1], kf, s[1][ct]);
  }
  const float scale = 0.1767766952966369f;  // 32^-0.5
  #pragma unroll
  for (int mt = 0; mt < 2; ++mt)
    #pragma unroll
    for (int rg = 0; rg < 4; ++rg) {
      float mx = -1e30f;
      #pragma unroll
      for (int ct = 0; ct < 8; ++ct) { s[mt][ct][rg] *= scale; mx = fmaxf(mx, s[mt][ct][rg]); }
      #pragma unroll
      for (int off = 1; off < 16; off <<= 1) mx = fmaxf(mx, __shfl_xor(mx, off));
      float sum = 0.f;
      #pragma unroll
      for (int ct = 0; ct < 8; ++ct) { float pv = __expf(s[mt][ct][rg] - mx); s[mt][ct][rg] = pv; sum += pv; }
      #pragma unroll
      for (int off = 1; off < 16; off <<= 1) sum += __shfl_xor(sum, off);
      float inv = 1.f / sum;
      int row = w * 32 + mt * 16 + (lane >> 4) * 4 + rg;
      #pragma unroll
      for (int ct = 0; ct < 8; ++ct) Pl[row][ct * 16 + (lane & 15)] = f2bf(s[mt][ct][rg] * inv);
    }
  __syncthreads();
  f32x4 o[2][2] = {};
  #pragma unroll
  for (int kk = 0; kk < 4; ++kk) {
    bf16x8v pa[2];
    #pragma unroll
    for (int mt = 0; mt < 2; ++mt)
      pa[mt] = *(const bf16x8v*)&Pl[w * 32 + mt * 16 + (lane & 15)][kk * 32 + (lane >> 4) * 8];
    #pragma unroll
    for (int nt = 0; nt < 2; ++nt) {
      bf16x8v vb;
      #pragma unroll
      for (int e = 0; e < 8; ++e) vb[e] = (short)Vl[kk * 32 + (lane >> 4) * 8 + e][nt * 16 + (lane & 15)];
      o[0][nt] = MFMA16(pa[0], vb, o[0][nt]);
      o[1][nt] = MFMA16(pa[1], vb, o[1][nt]);
    }
  }
  #pragma unroll
  for (int mt = 0; mt < 2; ++mt)
    #pragma unroll
    for (int nt = 0; nt < 2; ++nt)
      #pragma unroll
      for (int rg = 0; rg < 4; ++rg) {
        int row = w * 32 + mt * 16 + (lane >> 4) * 4 + rg;
        int dh = nt * 16 + (lane & 15);
        outc[((size_t)(l * R_ + row)) * 256 + h * 32 + dh] = f2bf(o[mt][nt][rg]);
      }
}

// ---------------- fused pair-bias LN + height softmax: one block per i ----------------
__global__ __launch_bounds__(512) void pairsm_kernel(const float* __restrict__ pair,
                                                     const float* __restrict__ wprime,
                                                     const float* __restrict__ wc,
                                                     const float* __restrict__ dots,
                                                     u16* __restrict__ attn) {
  int i = blockIdx.x;
  int tid = threadIdx.x, lane = tid & 63, w = tid >> 6;
  __shared__ float bias_s[384][9];
  int sub = lane & 15, g = lane >> 4;

  float4 wv[16];
  #pragma unroll
  for (int c = 0; c < 8; ++c) {
    wv[c * 2]     = *(const float4*)(wprime + (sub * 8 + c) * 8);
    wv[c * 2 + 1] = *(const float4*)(wprime + (sub * 8 + c) * 8 + 4);
  }

  #pragma unroll 1
  for (int pass = 0; pass < 12; ++pass) {
    int j = pass * 32 + w * 4 + g;
    const float* px = pair + ((size_t)i * L_ + j) * 128 + sub * 8;
    float4 a = *(const float4*)px;
    float4 b = *(const float4*)(px + 4);
    float xa[8] = {a.x, a.y, a.z, a.w, b.x, b.y, b.z, b.w};
    float s1 = 0.f, s2 = 0.f;
    float t0 = 0, t1 = 0, t2 = 0, t3 = 0, t4 = 0, t5 = 0, t6 = 0, t7 = 0;
    #pragma unroll
    for (int c = 0; c < 8; ++c) {
      float xv = xa[c];
      s1 += xv; s2 += xv * xv;
      t0 += wv[c * 2].x * xv; t1 += wv[c * 2].y * xv;
      t2 += wv[c * 2].z * xv; t3 += wv[c * 2].w * xv;
      t4 += wv[c * 2 + 1].x * xv; t5 += wv[c * 2 + 1].y * xv;
      t6 += wv[c * 2 + 1].z * xv; t7 += wv[c * 2 + 1].w * xv;
    }
    #pragma unroll
    for (int off = 1; off < 16; off <<= 1) {
      s1 += __shfl_xor(s1, off); s2 += __shfl_xor(s2, off);
      t0 += __shfl_xor(t0, off); t1 += __shfl_xor(t1, off);
      t2 += __shfl_xor(t2, off); t3 += __shfl_xor(t3, off);
      t4 += __shfl_xor(t4, off); t5 += __shfl_xor(t5, off);
      t6 += __shfl_xor(t6, off); t7 += __shfl_xor(t7, off);
    }
    if (sub < 8) {
      float mu = s1 * (1.f / 128.f);
      float rstd = rsqrtf(s2 * (1.f / 128.f) - mu * mu + 1e-5f);
      float tv = t0;
      if (sub == 1) tv = t1; if (sub == 2) tv = t2; if (sub == 3) tv = t3;
      if (sub == 4) tv = t4; if (sub == 5) tv = t5; if (sub == 6) tv = t6;
      if (sub == 7) tv = t7;
      bias_s[j][sub] = rstd * (tv - mu * wc[sub]) + wc[8 + sub];
    }
  }
  __syncthreads();

  int h = w;
  const float* dr = dots + ((size_t)h * L_ + i) * L_;
  float v[6];
  #pragma unroll
  for (int u = 0; u < 6; ++u) v[u] = dr[lane + u * 64] + bias_s[lane + u * 64][h];
  float mx = v[0];
  #pragma unroll
  for (int u = 1; u < 6; ++u) mx = fmaxf(mx, v[u]);
  #pragma unroll
  for (int off = 1; off < 64; off <<= 1) mx = fmaxf(mx, __shfl_xor(mx, off));
  float s = 0.f;
  #pragma unroll
  for (int u = 0; u < 6; ++u) { v[u] = __expf(v[u] - mx); s += v[u]; }
  #pragma unroll
  for (int off = 1; off < 64; off <<= 1) s += __shfl_xor(s, off);
  float inv = 1.f / s;
  #pragma unroll
  for (int u = 0; u < 6; ++u)
    attn[((size_t)h * L_ + i) * L_ + lane + u * 64] = f2bf(v[u] * inv);
}

// ---------------- V transpose for height: vt[(h*128+r)*32+d][j] = v[r,h,j,d] ----------------
__global__ __launch_bounds__(256) void vt_kernel(const u16* __restrict__ proj,
                                                 u16* __restrict__ vt) {
  int bz = blockIdx.x;
  int jc = bz % 6, hr = bz / 6;
  int h = hr >> 7, r = hr & 127;
  int j0 = jc * 64;
  __shared__ u16 T[64][40];
  int t = threadIdx.x;
  {
    int jr = t >> 2, seg = t & 3;
    *(uint4*)&T[jr][seg * 8] =
        *(const uint4*)(proj + ((size_t)(r * L_ + j0 + jr)) * 768 + 512 + h * 32 + seg * 8);
  }
  __syncthreads();
  {
    int dr = t >> 3, sg = t & 7;
    u16 tmp[8];
    #pragma unroll
    for (int u = 0; u < 8; ++u) tmp[u] = T[sg * 8 + u][dr];
    uint4 pk;
    pk.x = (unsigned)tmp[0] | ((unsigned)tmp[1] << 16);
    pk.y = (unsigned)tmp[2] | ((unsigned)tmp[3] << 16);
    pk.z = (unsigned)tmp[4] | ((unsigned)tmp[5] << 16);
    pk.w = (unsigned)tmp[6] | ((unsigned)tmp[7] << 16);
    *(uint4*)(vt + ((size_t)hr * 32 + dr) * 384 + j0 + sg * 8) = pk;
  }
}

// =====================================================================
extern "C" void kernel_launch(void* const* d_in, const int* in_sizes, int n_in,
                              void* d_out, int out_size, void* d_ws, size_t ws_size,
                              hipStream_t stream) {
  const float* x      = (const float*)d_in[0];
  const float* pair   = (const float*)d_in[1];
  const float* ln1_g  = (const float*)d_in[2];
  const float* ln1_b  = (const float*)d_in[3];
  const float* wq_w   = (const float*)d_in[4];
  const float* wkv_w  = (const float*)d_in[5];
  const float* wout_w = (const float*)d_in[6];
  const float* wout_b = (const float*)d_in[7];
  const float* hq_w   = (const float*)d_in[8];
  const float* hkv_w  = (const float*)d_in[9];
  const float* hout_w = (const float*)d_in[10];
  const float* hout_b = (const float*)d_in[11];
  const float* pn_g   = (const float*)d_in[12];
  const float* pn_b   = (const float*)d_in[13];
  const float* pl_w   = (const float*)d_in[14];
  const float* ln2_g  = (const float*)d_in[15];
  const float* ln2_b  = (const float*)d_in[16];
  const float* ff_w1  = (const float*)d_in[17];
  const float* ff_b1  = (const float*)d_in[18];
  const float* ff_w2  = (const float*)d_in[19];
  const float* ff_b2  = (const float*)d_in[20];

  char* ws = (char*)d_ws;
  u16* xnA   = (u16*)(ws + A_OFF);
  u16* projB = (u16*)(ws + B_OFF);
  u16* hattB = (u16*)(ws + B_OFF);            // height attn out overlays dead proj
  u16* attC  = (u16*)(ws + C_OFF);
  float* dotsD = (float*)(ws + D_OFF);
  u16* attnF = (u16*)(ws + F_OFF);
  u16* wqkvT_w = (u16*)(ws + EW_W);
  u16* wqkvT_h = (u16*)(ws + EW_H);
  u16* oT    = (u16*)(ws + EW_OT);
  u16* ff1T  = (u16*)(ws + EW_FF1);
  u16* ff2T  = (u16*)(ws + EW_FF2);
  float* wprime = (float*)(ws + EW_WP);
  float* wc     = (float*)(ws + EW_WC);
  float* bsum   = (float*)(ws + EW_BS);
  float* outF = (float*)d_out;
  constexpr int KBIG = 1 << 30;

  // --- single batched prep launch: all transposes + pairprep ---
  prep_kernel<<<dim3(4097), dim3(256), 0, stream>>>(
      wq_w, wkv_w, hq_w, hkv_w, ff_w1, ff_w2, wout_w, hout_w,
      wqkvT_w, wqkvT_h, ff1T, ff2T, oT,
      pn_g, pn_b, pl_w, wout_b, hout_b, wprime, wc, bsum);

  hipMemsetAsync(dotsD, 0, (size_t)H_ * L_ * L_ * 4, stream);

  // --- LN1 ---
  ln1_kernel<<<dim3(RL_ / 4), dim3(256), 0, stream>>>(x, ln1_g, ln1_b, xnA);

  // --- width projection (l-major output): projW[l*R+r] = xn[r*L+l] @ [wq|wkv] ---
  gemm128_kernel<<<dim3(384, 6, 1), dim3(256), 0, stream>>>(
      xnA, xnA, wqkvT_w, projB, nullptr, RL_, 768, 256,
      256, 32LL, 256, 32LL, 768, 32LL, 0LL, 0LL, 0LL, KBIG, 1 /*permA: l-major*/,
      1, 0LL, 0LL, 0LL, 0LL, 0LL, 0LL, 1.f, 1 /*bf16*/);

  // --- width fused attention (l-major in/out) -> attC ---
  wattn_kernel<<<dim3(L_ * H_), dim3(256), 0, stream>>>(projB, attC);

  // --- height projection (standard layout) ---
  gemm128_kernel<<<dim3(384, 6, 1), dim3(256), 0, stream>>>(
      xnA, xnA, wqkvT_h, projB, nullptr, RL_, 768, 256,
      256, 32LL, 256, 32LL, 768, 32LL, 0LL, 0LL, 0LL, KBIG, 0,
      1, 0LL, 0LL, 0LL, 0LL, 0LL, 0LL, 1.f, 1);

  // --- height dots: per head, split-K x4, atomic accumulate, alpha = 1/64 ---
  gemm128_kernel<<<dim3(3, 3, 32), dim3(256), 0, stream>>>(
      projB, projB, projB, dotsD, nullptr, 384, 384, 1024,
      768, (long long)L_ * 768, 768, (long long)L_ * 768, 384, 32LL,
      0LL, 256LL, 0LL, KBIG, 0,
      4, 32LL, 32LL * L_ * 768, 32LL, 32LL * L_ * 768,
      (long long)L_ * L_, 0LL, 1.f / 64.f, 8 /*atomic*/);

  // --- fused pair-bias LN + height softmax -> attn bf16 ---
  pairsm_kernel<<<dim3(L_), dim3(512), 0, stream>>>(pair, wprime, wc, dotsD, attnF);

  // --- V transpose (into A region; xn no longer needed) ---
  vt_kernel<<<dim3(H_ * R_ * 6), dim3(256), 0, stream>>>(projB, xnA);

  // --- ho: per head OUT[i][(r,d)] = attn[h] @ vt[h]^T -> hattB (B region) ---
  gemm128_kernel<<<dim3(3, 32, 8), dim3(256), 0, stream>>>(
      attnF, attnF, xnA, hattB, nullptr, 384, 4096, 384,
      384, 32LL, 384, 32LL, 256, (long long)L_ * 256,
      0LL, 0LL, 0LL, KBIG, 0,
      8, 0LL, (long long)L_ * L_, 0LL, 1572864LL, 0LL, 32LL, 1.f, 1 /*bf16*/);

  // --- fused out-proj: d_out = attC(l-major, permA=2)@woutT + hattB@houtT + bsum ---
  gemm128_kernel<<<dim3(384, 2, 1), dim3(256), 0, stream>>>(
      attC, hattB, oT, outF, bsum, RL_, 256, 512,
      256, 32LL, 512, 32LL, 256, 32LL, 0LL, 0LL, 0LL, 8 /*ksplit*/, 2 /*permA*/,
      1, 0LL, 0LL, 0LL, 0LL, 0LL, 0LL, 1.f, 0);

  // --- residual + LN2 -> xn2 (A region) ---
  resln_kernel<<<dim3(RL_ / 4), dim3(256), 0, stream>>>(x, outF, ln2_g, ln2_b, xnA);

  // --- FFN v6: d_out += relu(xn2@W1+b1)@W2 + b2 ---
  ffn_kernel<<<dim3(256), dim3(768), 0, stream>>>(
      xnA, ff1T, ff_b1, ff2T, ff_b2, outF);
}